// Round 1
// baseline (2258.622 us; speedup 1.0000x reference)
//
#include <hip/hip_runtime.h>

#define HD 64   // hidden size

__device__ __forceinline__ float fsig(float x) {
    return 1.0f / (1.0f + __expf(-x));
}
__device__ __forceinline__ float ftanh(float x) {
    // 1 - 2/(exp(2x)+1): saturates correctly at +/-1, abs err ~1e-7
    return 1.0f - 2.0f / (__expf(2.0f * x) + 1.0f);
}

// One workgroup per batch element b.
// Threads   0..255: layer-0 gate rows (k = tid), hold Whh0[k,:] in VGPRs.
// Threads 256..511: layer-1 gate rows (k = tid-256), hold Whh1[k,:] + Wih1[k,:].
// Lag-1 software pipeline: iteration i computes layer0 @ t=i and layer1 @ t=i-1.
__launch_bounds__(512, 2)
__global__ void lstm2_kernel(const float* __restrict__ x,     // [B,T]
                             const float* __restrict__ h0in,  // [2,B,HD]
                             const float* __restrict__ c0in,  // [2,B,HD]
                             const float* __restrict__ Wih0,  // [4H,1]
                             const float* __restrict__ Whh0,  // [4H,HD]
                             const float* __restrict__ bih0,
                             const float* __restrict__ bhh0,
                             const float* __restrict__ Wih1,  // [4H,HD]
                             const float* __restrict__ Whh1,  // [4H,HD]
                             const float* __restrict__ bih1,
                             const float* __restrict__ bhh1,
                             const float* __restrict__ Wlin,  // [1,HD]
                             const float* __restrict__ blin,  // [1]
                             float* __restrict__ out,         // [B,T]
                             int B, int T)
{
    const int b   = blockIdx.x;
    const int tid = threadIdx.x;
    const int k   = tid & 255;   // gate row within layer
    const int j   = tid & 63;    // hidden unit index (update waves)
    const bool g1 = (tid >= 256);

    __shared__ float h0buf[2][HD];   // layer0 h (== layer1 input), dbuf by t&1
    __shared__ float h1buf[2][HD];   // layer1 h, dbuf by t&1
    __shared__ float gb0[4 * HD];    // activated gates, layer0
    __shared__ float gb1[4 * HD];    // activated gates, layer1

    float wA[HD];          // Whh row (both groups)
    float wB[HD];          // Wih1 row (layer-1 group only)
    float bias;
    float wx0 = 0.0f;

    if (!g1) {
        const float4* wp = (const float4*)(Whh0 + k * HD);
        #pragma unroll
        for (int q = 0; q < HD / 4; ++q) {
            float4 v = wp[q];
            wA[4*q+0] = v.x; wA[4*q+1] = v.y; wA[4*q+2] = v.z; wA[4*q+3] = v.w;
        }
        bias = bih0[k] + bhh0[k];
        wx0  = Wih0[k];              // input dim is 1
    } else {
        const float4* wp = (const float4*)(Whh1 + k * HD);
        const float4* up = (const float4*)(Wih1 + k * HD);
        #pragma unroll
        for (int q = 0; q < HD / 4; ++q) {
            float4 v = wp[q];
            wA[4*q+0] = v.x; wA[4*q+1] = v.y; wA[4*q+2] = v.z; wA[4*q+3] = v.w;
            float4 u = up[q];
            wB[4*q+0] = u.x; wB[4*q+1] = u.y; wB[4*q+2] = u.z; wB[4*q+3] = u.w;
        }
        bias = bih1[k] + bhh1[k];
    }

    // cell state lives in registers of the two update waves
    float cst = 0.0f;
    if (tid < HD)                     cst = c0in[b * HD + j];            // layer0
    if (tid >= 256 && tid < 256 + HD) cst = c0in[B * HD + b * HD + j];   // layer1

    // initial h into slot 1 (read as slot (t-1)&1 with t=0)
    if (tid < HD)                      h0buf[1][j] = h0in[b * HD + j];
    else if (tid >= 256 && tid < 320)  h1buf[1][j] = h0in[B * HD + b * HD + j];

    const float wl    = Wlin[j];
    const float blin0 = blin[0];

    __syncthreads();

    for (int i = 0; i <= T; ++i) {
        // ---- Phase A: gate pre-activations + activations ----
        if (!g1) {
            if (i < T) {                                  // layer0, t = i
                const float xv = x[b * T + i];
                const float4* hp = (const float4*)(h0buf[(i + 1) & 1]); // h0(t-1)
                float acc = bias + wx0 * xv;
                #pragma unroll
                for (int q = 0; q < HD / 4; ++q) {
                    float4 hv = hp[q];
                    acc += wA[4*q+0]*hv.x + wA[4*q+1]*hv.y
                         + wA[4*q+2]*hv.z + wA[4*q+3]*hv.w;
                }
                gb0[k] = (k < 128 || k >= 192) ? fsig(acc) : ftanh(acc);
            }
        } else {
            if (i >= 1) {                                 // layer1, t = i-1
                const int t = i - 1;
                const float4* yp = (const float4*)(h0buf[t & 1]);       // y0(t)
                const float4* hp = (const float4*)(h1buf[(t + 1) & 1]); // h1(t-1)
                float acc = bias;
                #pragma unroll
                for (int q = 0; q < HD / 4; ++q) {
                    float4 yv = yp[q];
                    float4 hv = hp[q];
                    acc += wB[4*q+0]*yv.x + wB[4*q+1]*yv.y
                         + wB[4*q+2]*yv.z + wB[4*q+3]*yv.w
                         + wA[4*q+0]*hv.x + wA[4*q+1]*hv.y
                         + wA[4*q+2]*hv.z + wA[4*q+3]*hv.w;
                }
                gb1[k] = (k < 128 || k >= 192) ? fsig(acc) : ftanh(acc);
            }
        }
        __syncthreads();

        // ---- Phase B: c/h update (wave 0 per layer), output head ----
        if (tid < HD) {
            if (i < T) {
                float ai = gb0[j], af = gb0[HD + j], ag = gb0[2*HD + j], ao = gb0[3*HD + j];
                cst = af * cst + ai * ag;
                float h = ao * ftanh(cst);
                h0buf[i & 1][j] = h;
            }
        } else if (tid >= 256 && tid < 256 + HD) {
            if (i >= 1) {
                const int t = i - 1;
                float ai = gb1[j], af = gb1[HD + j], ag = gb1[2*HD + j], ao = gb1[3*HD + j];
                cst = af * cst + ai * ag;
                float h = ao * ftanh(cst);
                h1buf[t & 1][j] = h;
                // output head: dot(Wlin, h1) + blin, 64-lane butterfly reduce
                float p = wl * h;
                #pragma unroll
                for (int m = 32; m >= 1; m >>= 1) p += __shfl_xor(p, m, 64);
                if (j == 0) out[b * T + t] = p + blin0;
            }
        }
        __syncthreads();
    }
}

extern "C" void kernel_launch(void* const* d_in, const int* in_sizes, int n_in,
                              void* d_out, int out_size, void* d_ws, size_t ws_size,
                              hipStream_t stream)
{
    const float* x    = (const float*)d_in[0];
    const float* h0   = (const float*)d_in[1];
    const float* c0   = (const float*)d_in[2];
    const float* Wih0 = (const float*)d_in[3];
    const float* Whh0 = (const float*)d_in[4];
    const float* bih0 = (const float*)d_in[5];
    const float* bhh0 = (const float*)d_in[6];
    const float* Wih1 = (const float*)d_in[7];
    const float* Whh1 = (const float*)d_in[8];
    const float* bih1 = (const float*)d_in[9];
    const float* bhh1 = (const float*)d_in[10];
    const float* Wlin = (const float*)d_in[11];
    const float* blin = (const float*)d_in[12];
    float* out = (float*)d_out;

    const int B = in_sizes[1] / (2 * HD);   // h0 is [2,B,HD]
    const int T = in_sizes[0] / B;          // input is [B,T]

    lstm2_kernel<<<dim3(B), dim3(512), 0, stream>>>(
        x, h0, c0, Wih0, Whh0, bih0, bhh0,
        Wih1, Whh1, bih1, bhh1, Wlin, blin, out, B, T);
}

// Round 2
// 1759.955 us; speedup vs baseline: 1.2833x; 1.2833x over previous
//
#include <hip/hip_runtime.h>

#define HD 64
#define L2E 1.4426950408889634f

__device__ __forceinline__ float fexp2(float x) { return __builtin_amdgcn_exp2f(x); }
__device__ __forceinline__ float frcp(float x)  { return __builtin_amdgcn_rcpf(x); }
__device__ __forceinline__ float ftanh_fast(float x) {
    return 1.0f - 2.0f * frcp(fexp2(2.0f * L2E * x) + 1.0f);
}

// One workgroup per batch element. 768 threads = 12 waves, 3 groups of 4:
//   A (waves 0-3):  layer-0 gate rows, step t = i
//   B (waves 4-7):  layer-1 input projection xproj(t) = Wih1*y0(t)+biases, t = i-1
//   C (waves 8-11): layer-1 recurrent gates = Whh1*h1(t-1) + xproj(t), t = i-2
// Every thread: one 64-FMA dot, 4 accumulators. Gate remap: lane = 4*(j%16)+gate,
// unit j = 16*(wave%4)+(lane>>2) -> all 4 gates of unit j adjacent in one wave,
// c/h update fused in-wave via shfl_xor. Single barrier per iteration; all
// cross-group dependencies are >=1 iteration apart (double-buffered LDS).
__launch_bounds__(768, 3)
__global__ void lstm2_kernel(const float* __restrict__ x,     // [B,T]
                             const float* __restrict__ h0in,  // [2,B,HD]
                             const float* __restrict__ c0in,  // [2,B,HD]
                             const float* __restrict__ Wih0,  // [4H,1]
                             const float* __restrict__ Whh0,  // [4H,HD]
                             const float* __restrict__ bih0,
                             const float* __restrict__ bhh0,
                             const float* __restrict__ Wih1,  // [4H,HD]
                             const float* __restrict__ Whh1,  // [4H,HD]
                             const float* __restrict__ bih1,
                             const float* __restrict__ bhh1,
                             const float* __restrict__ Wlin,  // [1,HD]
                             const float* __restrict__ blin,  // [1]
                             float* __restrict__ out,         // [B,T]
                             int B, int T)
{
    const int b    = blockIdx.x;
    const int tid  = threadIdx.x;
    const int wave = tid >> 6;
    const int lane = tid & 63;
    const int gg   = lane & 3;                    // gate: 0=i 1=f 2=g 3=o
    const int j    = (wave & 3) * 16 + (lane >> 2); // hidden unit
    const int rA   = gg * HD + j;                 // remapped gate row (A, C)
    const int rB   = tid - 256;                   // natural row (B)

    const bool isA = (wave < 4);
    const bool isB = (wave >= 4 && wave < 8);
    const bool isC = (wave >= 8);

    __shared__ float h0buf[2][HD];
    __shared__ float h1buf[2][HD];
    __shared__ float xbuf[2][4 * HD];
    __shared__ __align__(16) float opart[2][4];

    float w[HD];
    float bias = 0.f, wx0 = 0.f, cst = 0.f, wl = 0.f;

    // branchless activation: act = c1 + c2 * rcp(exp2(aa*x) + 1)
    //   sigmoid (gg!=2): aa=-L2E, c1=0, c2=1
    //   tanh    (gg==2): aa=2*L2E, c1=1, c2=-2
    const float aa = (gg == 2) ? 2.f * L2E : -L2E;
    const float c1 = (gg == 2) ? 1.f : 0.f;
    const float c2 = (gg == 2) ? -2.f : 1.f;

    if (isA) {
        const float4* wp = (const float4*)(Whh0 + rA * HD);
        #pragma unroll
        for (int q = 0; q < 16; ++q) {
            float4 v = wp[q];
            w[4*q] = v.x; w[4*q+1] = v.y; w[4*q+2] = v.z; w[4*q+3] = v.w;
        }
        bias = bih0[rA] + bhh0[rA];
        wx0  = Wih0[rA];
        if (gg == 0) cst = c0in[b * HD + j];
    } else if (isB) {
        const float4* wp = (const float4*)(Wih1 + rB * HD);
        #pragma unroll
        for (int q = 0; q < 16; ++q) {
            float4 v = wp[q];
            w[4*q] = v.x; w[4*q+1] = v.y; w[4*q+2] = v.z; w[4*q+3] = v.w;
        }
        bias = bih1[rB] + bhh1[rB];
    } else {
        const float4* wp = (const float4*)(Whh1 + rA * HD);
        #pragma unroll
        for (int q = 0; q < 16; ++q) {
            float4 v = wp[q];
            w[4*q] = v.x; w[4*q+1] = v.y; w[4*q+2] = v.z; w[4*q+3] = v.w;
        }
        if (gg == 0) cst = c0in[B * HD + b * HD + j];
        wl = Wlin[j];
    }

    if (tid < HD)            h0buf[1][tid]      = h0in[b * HD + tid];
    else if (tid < 2 * HD)   h1buf[1][tid - HD] = h0in[B * HD + b * HD + (tid - HD)];

    const float blin0 = blin[0];
    float xchunk = 0.f;

    for (int i = 0; i <= T + 2; ++i) {
        __syncthreads();

        if (isA && i < T) {                       // layer 0, t = i
            if ((i & 63) == 0) {
                int idx = i + lane; if (idx >= T) idx = T - 1;
                xchunk = x[b * T + idx];
            }
            float xv = __shfl(xchunk, i & 63, 64);
            const float4* hp = (const float4*)(h0buf[(i + 1) & 1]);
            float a0 = fmaf(wx0, xv, bias), a1 = 0.f, a2 = 0.f, a3 = 0.f;
            #pragma unroll
            for (int q = 0; q < 16; ++q) {
                float4 hv = hp[q];
                a0 = fmaf(w[4*q],   hv.x, a0);
                a1 = fmaf(w[4*q+1], hv.y, a1);
                a2 = fmaf(w[4*q+2], hv.z, a2);
                a3 = fmaf(w[4*q+3], hv.w, a3);
            }
            float acc = (a0 + a1) + (a2 + a3);
            float act = fmaf(c2, frcp(fexp2(acc * aa) + 1.f), c1);
            float vf = __shfl_xor(act, 1, 64);
            float vg = __shfl_xor(act, 2, 64);
            float vo = __shfl_xor(act, 3, 64);
            cst = fmaf(vf, cst, act * vg);        // valid on gg==0 lanes
            float h = vo * ftanh_fast(cst);
            if (gg == 0) h0buf[i & 1][j] = h;
        }

        if (isB && i >= 1 && i <= T) {            // layer-1 xproj, t = i-1
            const float4* yp = (const float4*)(h0buf[(i + 1) & 1]);
            float a0 = bias, a1 = 0.f, a2 = 0.f, a3 = 0.f;
            #pragma unroll
            for (int q = 0; q < 16; ++q) {
                float4 yv = yp[q];
                a0 = fmaf(w[4*q],   yv.x, a0);
                a1 = fmaf(w[4*q+1], yv.y, a1);
                a2 = fmaf(w[4*q+2], yv.z, a2);
                a3 = fmaf(w[4*q+3], yv.w, a3);
            }
            xbuf[(i - 1) & 1][rB] = (a0 + a1) + (a2 + a3);
        }

        if (isC && i >= 2 && i <= T + 1) {        // layer 1 recurrent, t = i-2
            const float4* hp = (const float4*)(h1buf[(i + 1) & 1]);
            float a0 = xbuf[i & 1][rA], a1 = 0.f, a2 = 0.f, a3 = 0.f;
            #pragma unroll
            for (int q = 0; q < 16; ++q) {
                float4 hv = hp[q];
                a0 = fmaf(w[4*q],   hv.x, a0);
                a1 = fmaf(w[4*q+1], hv.y, a1);
                a2 = fmaf(w[4*q+2], hv.z, a2);
                a3 = fmaf(w[4*q+3], hv.w, a3);
            }
            float acc = (a0 + a1) + (a2 + a3);
            float act = fmaf(c2, frcp(fexp2(acc * aa) + 1.f), c1);
            float vf = __shfl_xor(act, 1, 64);
            float vg = __shfl_xor(act, 2, 64);
            float vo = __shfl_xor(act, 3, 64);
            cst = fmaf(vf, cst, act * vg);
            float h = vo * ftanh_fast(cst);
            if (gg == 0) h1buf[i & 1][j] = h;
            float p = (gg == 0) ? wl * h : 0.f;
            p += __shfl_xor(p, 4, 64);
            p += __shfl_xor(p, 8, 64);
            p += __shfl_xor(p, 16, 64);
            p += __shfl_xor(p, 32, 64);
            if (lane == 0) opart[i & 1][wave & 3] = p;
        }

        if (tid == 256 && i >= 3) {               // output store, t = i-3
            float4 op = *((const float4*)opart[(i + 1) & 1]);
            out[b * T + (i - 3)] = op.x + op.y + op.z + op.w + blin0;
        }
    }
}

extern "C" void kernel_launch(void* const* d_in, const int* in_sizes, int n_in,
                              void* d_out, int out_size, void* d_ws, size_t ws_size,
                              hipStream_t stream)
{
    const float* x    = (const float*)d_in[0];
    const float* h0   = (const float*)d_in[1];
    const float* c0   = (const float*)d_in[2];
    const float* Wih0 = (const float*)d_in[3];
    const float* Whh0 = (const float*)d_in[4];
    const float* bih0 = (const float*)d_in[5];
    const float* bhh0 = (const float*)d_in[6];
    const float* Wih1 = (const float*)d_in[7];
    const float* Whh1 = (const float*)d_in[8];
    const float* bih1 = (const float*)d_in[9];
    const float* bhh1 = (const float*)d_in[10];
    const float* Wlin = (const float*)d_in[11];
    const float* blin = (const float*)d_in[12];
    float* out = (float*)d_out;

    const int B = in_sizes[1] / (2 * HD);   // h0 is [2,B,HD]
    const int T = in_sizes[0] / B;          // input is [B,T]

    lstm2_kernel<<<dim3(B), dim3(768), 0, stream>>>(
        x, h0, c0, Wih0, Whh0, bih0, bhh0,
        Wih1, Whh1, bih1, bhh1, Wlin, blin, out, B, T);
}